// Round 2
// baseline (842.585 us; speedup 1.0000x reference)
//
#include <hip/hip_runtime.h>
#include <math.h>

#define LVLS 8
#define TSZ (1u << 19)

struct ResArr { float r[8]; };

__device__ __forceinline__ float relu_f(float x) { return fmaxf(x, 0.0f); }

// f32 -> bf16 bits, round-to-nearest-even
__device__ __forceinline__ unsigned short f2b(float x) {
    unsigned u = __float_as_uint(x);
    return (unsigned short)((u + 0x7fffu + ((u >> 16) & 1u)) >> 16);
}
// bf16 bits -> f32
__device__ __forceinline__ float b2f(unsigned short b) {
    return __uint_as_float(((unsigned)b) << 16);
}

// acc[j] = b[j] + sum_{k<IN} act[k][tid] * W[k*64+j]
// W/b wave-uniform -> scalar loads; act -> ds_read_u16 + shl.
__device__ __forceinline__ void dense64(const float* __restrict__ W,
                                        const float* __restrict__ b,
                                        const unsigned short (*actc)[64], int IN,
                                        int tid, float acc[64])
{
#pragma unroll
    for (int j = 0; j < 64; ++j) acc[j] = b[j];
    for (int k = 0; k < IN; ++k) {
        float a = b2f(actc[k][tid]);
        const float* wr = W + k * 64;
#pragma unroll
        for (int j = 0; j < 64; ++j) acc[j] = fmaf(a, wr[j], acc[j]);
    }
}

__global__ void __launch_bounds__(64, 5) ngp_fused(
    const float* __restrict__ pts, const float* __restrict__ views,
    const float* __restrict__ tables,
    const float* __restrict__ W1, const float* __restrict__ b1,
    const float* __restrict__ W2, const float* __restrict__ b2,
    const float* __restrict__ W3, const float* __restrict__ b3,
    const float* __restrict__ W4, const float* __restrict__ b4,
    const float* __restrict__ W5, const float* __restrict__ b5,
    const float* __restrict__ W6, const float* __restrict__ b6,
    const float* __restrict__ W7, const float* __restrict__ b7,
    ResArr res, float* __restrict__ out_col, float* __restrict__ out_den,
    int npts)
{
    // activations bf16 [neuron][tid]: 8 KB -> 20 blocks/CU (LDS-limited).
    // Each thread touches only its own column -> no barriers needed.
    __shared__ unsigned short act[64][64];
    const int tid = threadIdx.x;
    const int n = blockIdx.x * 64 + tid;
    if (n >= npts) return;

    const float px = pts[3 * n + 0];
    const float py = pts[3 * n + 1];
    const float pz = pts[3 * n + 2];

    // ---- hash grid encode ----
#pragma unroll
    for (int l = 0; l < LVLS; ++l) {
        float r = res.r[l];
        float fx = px * r, fy = py * r, fz = pz * r;
        float f0x = floorf(fx), f0y = floorf(fy), f0z = floorf(fz);
        unsigned ix = (unsigned)f0x, iy = (unsigned)f0y, iz = (unsigned)f0z;
        float tx = fx - f0x, ty = fy - f0y, tz = fz - f0z;
        const float4* tbl = (const float4*)tables + (size_t)l * TSZ;
        float4 a = make_float4(0.f, 0.f, 0.f, 0.f);
#pragma unroll
        for (int c = 0; c < 8; ++c) {
            unsigned ux = ix + ((c >> 2) & 1);
            unsigned uy = iy + ((c >> 1) & 1);
            unsigned uz = iz + (c & 1);
            unsigned h = (ux * 1u) ^ (uy * 2654435761u) ^ (uz * 805459861u);
            h &= (TSZ - 1u);
            float4 f = tbl[h];
            float w = ((c & 4) ? tx : 1.0f - tx) *
                      ((c & 2) ? ty : 1.0f - ty) *
                      ((c & 1) ? tz : 1.0f - tz);
            a.x = fmaf(w, f.x, a.x);
            a.y = fmaf(w, f.y, a.y);
            a.z = fmaf(w, f.z, a.z);
            a.w = fmaf(w, f.w, a.w);
        }
        act[l * 4 + 0][tid] = f2b(a.x);
        act[l * 4 + 1][tid] = f2b(a.y);
        act[l * 4 + 2][tid] = f2b(a.z);
        act[l * 4 + 3][tid] = f2b(a.w);
    }

    float acc[64];

    // ---- density net ----
    dense64(W1, b1, act, 32, tid, acc);
#pragma unroll
    for (int j = 0; j < 64; ++j) act[j][tid] = f2b(relu_f(acc[j]));

    dense64(W2, b2, act, 64, tid, acc);
#pragma unroll
    for (int j = 0; j < 64; ++j) act[j][tid] = f2b(relu_f(acc[j]));

    float acc3[16];
#pragma unroll
    for (int j = 0; j < 16; ++j) acc3[j] = b3[j];
    for (int k = 0; k < 64; ++k) {
        float aa = b2f(act[k][tid]);
        const float* wr = W3 + k * 16;
#pragma unroll
        for (int j = 0; j < 16; ++j) acc3[j] = fmaf(aa, wr[j], acc3[j]);
    }
    float density = relu_f(acc3[0]);

    // ---- SH4 view encoding ----
    float vx = views[3 * n + 0], vy = views[3 * n + 1], vz = views[3 * n + 2];
    float inv = rsqrtf(vx * vx + vy * vy + vz * vz);
    vx *= inv; vy *= inv; vz *= inv;
    float xx = vx * vx, yy = vy * vy, zz = vz * vz;
    float sh[16];
    sh[0]  = 0.28209479177387814f;
    sh[1]  = -0.48860251190291987f * vy;
    sh[2]  = 0.48860251190291987f * vz;
    sh[3]  = -0.48860251190291987f * vx;
    sh[4]  = 1.0925484305920792f * vx * vy;
    sh[5]  = -1.0925484305920792f * vy * vz;
    sh[6]  = 0.94617469575755997f * zz - 0.31539156525252005f;
    sh[7]  = -1.0925484305920792f * vx * vz;
    sh[8]  = 0.54627421529603959f * (xx - yy);
    sh[9]  = -0.59004358992664352f * vy * (3.0f * xx - yy);
    sh[10] = 2.8906114426405538f * vx * vy * vz;
    sh[11] = -0.45704579946446572f * vy * (4.0f * zz - xx - yy);
    sh[12] = 0.37317633259011546f * vz * (2.0f * zz - 3.0f * xx - 3.0f * yy);
    sh[13] = -0.45704579946446572f * vx * (4.0f * zz - xx - yy);
    sh[14] = 1.4453057213202769f * vz * (xx - yy);
    sh[15] = -0.59004358992664352f * vx * (xx - 3.0f * yy);

    // ---- color net input: [x3[1:16], sh[0:16]] = 31 dims ----
#pragma unroll
    for (int k = 0; k < 15; ++k) act[k][tid] = f2b(acc3[1 + k]);
#pragma unroll
    for (int k = 0; k < 16; ++k) act[15 + k][tid] = f2b(sh[k]);

    dense64(W4, b4, act, 31, tid, acc);
#pragma unroll
    for (int j = 0; j < 64; ++j) act[j][tid] = f2b(relu_f(acc[j]));

    dense64(W5, b5, act, 64, tid, acc);
#pragma unroll
    for (int j = 0; j < 64; ++j) act[j][tid] = f2b(relu_f(acc[j]));

    dense64(W6, b6, act, 64, tid, acc);
#pragma unroll
    for (int j = 0; j < 64; ++j) act[j][tid] = f2b(relu_f(acc[j]));

    float c3[3];
#pragma unroll
    for (int j = 0; j < 3; ++j) c3[j] = b7[j];
    for (int k = 0; k < 64; ++k) {
        float aa = b2f(act[k][tid]);
        const float* wr = W7 + k * 3;
#pragma unroll
        for (int j = 0; j < 3; ++j) c3[j] = fmaf(aa, wr[j], c3[j]);
    }

#pragma unroll
    for (int j = 0; j < 3; ++j)
        out_col[3 * (size_t)n + j] = 1.0f / (1.0f + expf(-c3[j]));
    out_den[n] = density;
}

extern "C" void kernel_launch(void* const* d_in, const int* in_sizes, int n_in,
                              void* d_out, int out_size, void* d_ws, size_t ws_size,
                              hipStream_t stream) {
    const float* pts    = (const float*)d_in[0];
    const float* views  = (const float*)d_in[1];
    const float* tables = (const float*)d_in[2];
    const float* W1 = (const float*)d_in[3];  const float* b1 = (const float*)d_in[4];
    const float* W2 = (const float*)d_in[5];  const float* b2 = (const float*)d_in[6];
    const float* W3 = (const float*)d_in[7];  const float* b3 = (const float*)d_in[8];
    const float* W4 = (const float*)d_in[9];  const float* b4 = (const float*)d_in[10];
    const float* W5 = (const float*)d_in[11]; const float* b5 = (const float*)d_in[12];
    const float* W6 = (const float*)d_in[13]; const float* b6 = (const float*)d_in[14];
    const float* W7 = (const float*)d_in[15]; const float* b7 = (const float*)d_in[16];

    const int N = in_sizes[0] / 3;
    float* out = (float*)d_out;
    float* out_col = out;                  // [N,3]
    float* out_den = out + (size_t)3 * N;  // [N]

    ResArr res;
    for (int l = 0; l < 8; ++l)
        res.r[l] = (float)(16.0 * pow(64.0, (double)l / 7.0));

    const int grid = (N + 63) / 64;
    ngp_fused<<<grid, 64, 0, stream>>>(pts, views, tables,
                                       W1, b1, W2, b2, W3, b3, W4, b4,
                                       W5, b5, W6, b6, W7, b7,
                                       res, out_col, out_den, N);
}

// Round 3
// 378.977 us; speedup vs baseline: 2.2233x; 2.2233x over previous
//
#include <hip/hip_runtime.h>
#include <math.h>

#define TSZ (1u << 19)
#define APAD 72  // activation row stride in bf16 elements (64 + 8 pad -> 2-way bank aliasing only)

typedef __attribute__((ext_vector_type(8))) short bf8_t;   // 8 bf16 = 4 VGPRs (MFMA A/B frag)
typedef __attribute__((ext_vector_type(4))) float f32x4;   // MFMA C/D frag

struct ResArr { float r[8]; };
struct WPtrs { const float* w[7]; };

// f32 -> bf16 bits, RNE
__device__ __forceinline__ unsigned short f2b(float x) {
    unsigned u = __float_as_uint(x);
    return (unsigned short)((u + 0x7fffu + ((u >> 16) & 1u)) >> 16);
}
__device__ __forceinline__ unsigned pack2(float a, float b) {
    return (unsigned)f2b(a) | ((unsigned)f2b(b) << 16);
}

// ---------------- pre-kernel: weights -> bf16 B-fragment order in d_ws ----------------
// Layer l fragment file: frag_id = nt*KS + ks; element (lane, j) = W[k][n], bf16,
// with k = ks*32 + (lane>>4)*8 + j, n = nt*16 + (lane&15). Zero-padded rows/cols.
// Element bases: L1:0 L2:2048 L3:6144 L4:7168 L5:9216 L6:13312 L7:17408, total 18432.
__global__ void prep_weights(WPtrs wp, unsigned short* __restrict__ out) {
    int idx = blockIdx.x * 256 + threadIdx.x;
    if (idx >= 18432) return;
    int layer, base;
    if      (idx < 2048)  { layer = 0; base = 0;     }
    else if (idx < 6144)  { layer = 1; base = 2048;  }
    else if (idx < 7168)  { layer = 2; base = 6144;  }
    else if (idx < 9216)  { layer = 3; base = 7168;  }
    else if (idx < 13312) { layer = 4; base = 9216;  }
    else if (idx < 17408) { layer = 5; base = 13312; }
    else                  { layer = 6; base = 17408; }
    int rel  = idx - base;
    int frag = rel >> 9;
    int r    = rel & 511;
    int lane = r >> 3, j = r & 7;
    int quad = lane >> 4, col16 = lane & 15;
    int KS = (layer == 0 || layer == 3) ? 1 : 2;
    int nt = frag / KS, ks = frag % KS;
    int k = ks * 32 + quad * 8 + j;
    int n = nt * 16 + col16;
    int Kreal = (layer == 0) ? 32 : (layer == 3) ? 31 : 64;
    int Nw    = (layer == 2) ? 16 : (layer == 6) ? 3  : 64;
    float v = 0.0f;
    if (k < Kreal && n < Nw) v = wp.w[layer][k * Nw + n];
    out[idx] = f2b(v);
}

// ---------------- main fused kernel ----------------
__global__ void __launch_bounds__(256, 2) ngp_mfma(
    const float* __restrict__ pts, const float* __restrict__ views,
    const float* __restrict__ tables,
    const unsigned short* __restrict__ wfrag,
    const float* __restrict__ b1, const float* __restrict__ b2,
    const float* __restrict__ b3, const float* __restrict__ b4,
    const float* __restrict__ b5, const float* __restrict__ b6,
    const float* __restrict__ b7,
    ResArr res, float* __restrict__ out_col, float* __restrict__ out_den,
    int npts)
{
    __shared__ unsigned short act[4][64 * APAD];   // per-wave activation tile, 36 KB total
    const int tid   = threadIdx.x;
    const int w     = tid >> 6;
    const int lane  = tid & 63;
    const int quad  = lane >> 4;
    const int col16 = lane & 15;
    unsigned short* actw = act[w];

    const int n0 = blockIdx.x * 256 + w * 64;      // this wave's point base
    if (n0 >= npts) return;
    int pt = n0 + lane;
    int ptc = pt < npts ? pt : npts - 1;           // clamp loads; stores guarded by row

    // ---- load point + view early ----
    const float px = pts[3 * ptc + 0];
    const float py = pts[3 * ptc + 1];
    const float pz = pts[3 * ptc + 2];
    float vx = views[3 * ptc + 0], vy = views[3 * ptc + 1], vz = views[3 * ptc + 2];

    // ---- hash grid encode: lane = point; write bf16 features to act[lane][0..31] ----
#pragma unroll
    for (int l = 0; l < 8; ++l) {
        float rr = res.r[l];
        float fx = px * rr, fy = py * rr, fz = pz * rr;
        float f0x = floorf(fx), f0y = floorf(fy), f0z = floorf(fz);
        unsigned ix = (unsigned)f0x, iy = (unsigned)f0y, iz = (unsigned)f0z;
        float tx = fx - f0x, ty = fy - f0y, tz = fz - f0z;
        const float4* tbl = (const float4*)tables + (size_t)l * TSZ;
        float4 a = make_float4(0.f, 0.f, 0.f, 0.f);
#pragma unroll
        for (int c = 0; c < 8; ++c) {
            unsigned ux = ix + ((c >> 2) & 1);
            unsigned uy = iy + ((c >> 1) & 1);
            unsigned uz = iz + (c & 1);
            unsigned h = (ux * 1u) ^ (uy * 2654435761u) ^ (uz * 805459861u);
            h &= (TSZ - 1u);
            float4 f = tbl[h];
            float wt = ((c & 4) ? tx : 1.0f - tx) *
                       ((c & 2) ? ty : 1.0f - ty) *
                       ((c & 1) ? tz : 1.0f - tz);
            a.x = fmaf(wt, f.x, a.x);
            a.y = fmaf(wt, f.y, a.y);
            a.z = fmaf(wt, f.z, a.z);
            a.w = fmaf(wt, f.w, a.w);
        }
        *(unsigned*)&actw[lane * APAD + l * 4 + 0] = pack2(a.x, a.y);
        *(unsigned*)&actw[lane * APAD + l * 4 + 2] = pack2(a.z, a.w);
    }

    // ---- SH4 (kept in regs until after layer 3) ----
    float inv = rsqrtf(vx * vx + vy * vy + vz * vz);
    vx *= inv; vy *= inv; vz *= inv;
    float xx = vx * vx, yy = vy * vy, zz = vz * vz;
    float sh[16];
    sh[0]  = 0.28209479177387814f;
    sh[1]  = -0.48860251190291987f * vy;
    sh[2]  = 0.48860251190291987f * vz;
    sh[3]  = -0.48860251190291987f * vx;
    sh[4]  = 1.0925484305920792f * vx * vy;
    sh[5]  = -1.0925484305920792f * vy * vz;
    sh[6]  = 0.94617469575755997f * zz - 0.31539156525252005f;
    sh[7]  = -1.0925484305920792f * vx * vz;
    sh[8]  = 0.54627421529603959f * (xx - yy);
    sh[9]  = -0.59004358992664352f * vy * (3.0f * xx - yy);
    sh[10] = 2.8906114426405538f * vx * vy * vz;
    sh[11] = -0.45704579946446572f * vy * (4.0f * zz - xx - yy);
    sh[12] = 0.37317633259011546f * vz * (2.0f * zz - 3.0f * xx - 3.0f * yy);
    sh[13] = -0.45704579946446572f * vx * (4.0f * zz - xx - yy);
    sh[14] = 1.4453057213202769f * vz * (xx - yy);
    sh[15] = -0.59004358992664352f * vx * (xx - 3.0f * yy);

    // ---- MLP layers (wave-cooperative MFMA; all A-frags read before any write) ----
    // standard 64-out layer, relu, result back into actw
#define LAYER_STD(KS, FB, BIAS)                                                          \
    {                                                                                    \
        bf8_t A[4][KS];                                                                  \
        _Pragma("unroll") for (int mt = 0; mt < 4; ++mt)                                 \
            _Pragma("unroll") for (int ks = 0; ks < KS; ++ks)                            \
                A[mt][ks] = *(const bf8_t*)&actw[(mt * 16 + col16) * APAD + ks * 32 + quad * 8]; \
        _Pragma("unroll") for (int nt = 0; nt < 4; ++nt) {                               \
            float bv = BIAS[nt * 16 + col16];                                            \
            f32x4 acc[4];                                                                \
            _Pragma("unroll") for (int mt = 0; mt < 4; ++mt) acc[mt] = f32x4{bv, bv, bv, bv}; \
            _Pragma("unroll") for (int ks = 0; ks < KS; ++ks) {                          \
                bf8_t B = ((const bf8_t*)(wfrag + FB + (nt * KS + ks) * 512))[lane];     \
                _Pragma("unroll") for (int mt = 0; mt < 4; ++mt)                         \
                    acc[mt] = __builtin_amdgcn_mfma_f32_16x16x32_bf16(A[mt][ks], B, acc[mt], 0, 0, 0); \
            }                                                                            \
            _Pragma("unroll") for (int mt = 0; mt < 4; ++mt)                             \
                _Pragma("unroll") for (int r = 0; r < 4; ++r) {                          \
                    int row = mt * 16 + quad * 4 + r;                                    \
                    actw[row * APAD + nt * 16 + col16] = f2b(fmaxf(acc[mt][r], 0.0f));   \
                }                                                                        \
        }                                                                                \
    }

    LAYER_STD(1, 0, b1)        // L1: 32 -> 64, relu
    LAYER_STD(2, 2048, b2)     // L2: 64 -> 64, relu

    // L3: 64 -> 16, no relu; col0 -> density, cols 1..15 -> act[.][0..14]
    {
        bf8_t A[4][2];
#pragma unroll
        for (int mt = 0; mt < 4; ++mt)
#pragma unroll
            for (int ks = 0; ks < 2; ++ks)
                A[mt][ks] = *(const bf8_t*)&actw[(mt * 16 + col16) * APAD + ks * 32 + quad * 8];
        float bv = b3[col16];
        f32x4 acc[4];
#pragma unroll
        for (int mt = 0; mt < 4; ++mt) acc[mt] = f32x4{bv, bv, bv, bv};
#pragma unroll
        for (int ks = 0; ks < 2; ++ks) {
            bf8_t B = ((const bf8_t*)(wfrag + 6144 + ks * 512))[lane];
#pragma unroll
            for (int mt = 0; mt < 4; ++mt)
                acc[mt] = __builtin_amdgcn_mfma_f32_16x16x32_bf16(A[mt][ks], B, acc[mt], 0, 0, 0);
        }
#pragma unroll
        for (int mt = 0; mt < 4; ++mt)
#pragma unroll
            for (int r = 0; r < 4; ++r) {
                int row = mt * 16 + quad * 4 + r;
                float v = acc[mt][r];
                if (col16 == 0) {
                    if (n0 + row < npts) out_den[n0 + row] = fmaxf(v, 0.0f);
                } else {
                    actw[row * APAD + (col16 - 1)] = f2b(v);
                }
            }
    }

    // color input cols 15..30 = sh, col 31 = 0 (W4 row 31 is zero anyway, but avoid NaN garbage)
#pragma unroll
    for (int i = 0; i < 16; ++i)
        actw[lane * APAD + 15 + i] = f2b(sh[i]);
    actw[lane * APAD + 31] = 0;

    LAYER_STD(1, 7168, b4)     // L4: 31(+pad) -> 64, relu
    LAYER_STD(2, 9216, b5)     // L5: 64 -> 64, relu
    LAYER_STD(2, 13312, b6)    // L6: 64 -> 64, relu

    // L7: 64 -> 3 (cols 3..15 are zero-weight pads), sigmoid, store colors
    {
        bf8_t A[4][2];
#pragma unroll
        for (int mt = 0; mt < 4; ++mt)
#pragma unroll
            for (int ks = 0; ks < 2; ++ks)
                A[mt][ks] = *(const bf8_t*)&actw[(mt * 16 + col16) * APAD + ks * 32 + quad * 8];
        float bv = (col16 < 3) ? b7[col16] : 0.0f;
        f32x4 acc[4];
#pragma unroll
        for (int mt = 0; mt < 4; ++mt) acc[mt] = f32x4{bv, bv, bv, bv};
#pragma unroll
        for (int ks = 0; ks < 2; ++ks) {
            bf8_t B = ((const bf8_t*)(wfrag + 17408 + ks * 512))[lane];
#pragma unroll
            for (int mt = 0; mt < 4; ++mt)
                acc[mt] = __builtin_amdgcn_mfma_f32_16x16x32_bf16(A[mt][ks], B, acc[mt], 0, 0, 0);
        }
        if (col16 < 3) {
#pragma unroll
            for (int mt = 0; mt < 4; ++mt)
#pragma unroll
                for (int r = 0; r < 4; ++r) {
                    int row = mt * 16 + quad * 4 + r;
                    if (n0 + row < npts) {
                        float s = 1.0f / (1.0f + expf(-acc[mt][r]));
                        out_col[(size_t)(n0 + row) * 3 + col16] = s;
                    }
                }
        }
    }
#undef LAYER_STD
}

extern "C" void kernel_launch(void* const* d_in, const int* in_sizes, int n_in,
                              void* d_out, int out_size, void* d_ws, size_t ws_size,
                              hipStream_t stream) {
    const float* pts    = (const float*)d_in[0];
    const float* views  = (const float*)d_in[1];
    const float* tables = (const float*)d_in[2];
    const float* W1 = (const float*)d_in[3];  const float* b1 = (const float*)d_in[4];
    const float* W2 = (const float*)d_in[5];  const float* b2 = (const float*)d_in[6];
    const float* W3 = (const float*)d_in[7];  const float* b3 = (const float*)d_in[8];
    const float* W4 = (const float*)d_in[9];  const float* b4 = (const float*)d_in[10];
    const float* W5 = (const float*)d_in[11]; const float* b5 = (const float*)d_in[12];
    const float* W6 = (const float*)d_in[13]; const float* b6 = (const float*)d_in[14];
    const float* W7 = (const float*)d_in[15]; const float* b7 = (const float*)d_in[16];

    const int N = in_sizes[0] / 3;
    float* out = (float*)d_out;
    float* out_col = out;                  // [N,3]
    float* out_den = out + (size_t)3 * N;  // [N]

    unsigned short* wfrag = (unsigned short*)d_ws;   // 18432 bf16 elements = 36864 B

    WPtrs wp;
    wp.w[0] = W1; wp.w[1] = W2; wp.w[2] = W3; wp.w[3] = W4;
    wp.w[4] = W5; wp.w[5] = W6; wp.w[6] = W7;
    prep_weights<<<(18432 + 255) / 256, 256, 0, stream>>>(wp, wfrag);

    ResArr res;
    for (int l = 0; l < 8; ++l)
        res.r[l] = (float)(16.0 * pow(64.0, (double)l / 7.0));

    const int grid = (N + 255) / 256;
    ngp_mfma<<<grid, 256, 0, stream>>>(pts, views, tables, wfrag,
                                       b1, b2, b3, b4, b5, b6, b7,
                                       res, out_col, out_den, N);
}